// Round 2
// baseline (8382.565 us; speedup 1.0000x reference)
//
#include <hip/hip_runtime.h>

// CapsNet forward, fp32, batch-chunked to fit unknown ws_size.
// Per-chunk ws layout (floats): [0, C*9216)              u (conv2 out, caps layout)
//                               [C*9216, C*193536)       u_hat [b][j*16+q][i]
//                               h1 aliases u_hat region (dead before u_hat written)

// ---------------- conv1 + ReLU: [C,1,28,28] -> [C,256,20,20] ----------------
// grid C*16 blocks, 320 threads; block = (b, 16 c_out), thread = (co, oy) -> 20 ox outputs
__global__ __launch_bounds__(320) void conv1_k(const float* __restrict__ in,
                                               const float* __restrict__ w,
                                               const float* __restrict__ bias,
                                               float* __restrict__ h1) {
    int blk = blockIdx.x;
    int b = blk >> 4;
    int c0 = (blk & 15) * 16;
    __shared__ float img[784];      // 28*28
    __shared__ float wl[16 * 81];
    __shared__ float bl[16];
    int tid = threadIdx.x;
    for (int t = tid; t < 784; t += 320) img[t] = in[b * 784 + t];
    for (int t = tid; t < 1296; t += 320) wl[t] = w[c0 * 81 + t];
    if (tid < 16) bl[tid] = bias[c0 + tid];
    __syncthreads();

    int co = tid / 20, oy = tid % 20;
    float wr[81];
#pragma unroll
    for (int k = 0; k < 81; k++) wr[k] = wl[co * 81 + k];
    float acc[20];
    float bv = bl[co];
#pragma unroll
    for (int ox = 0; ox < 20; ox++) acc[ox] = bv;

#pragma unroll
    for (int ky = 0; ky < 9; ky++) {
        const float* rp = &img[(oy + ky) * 28];
        float r[28];
#pragma unroll
        for (int v = 0; v < 7; v++) {
            float4 t4 = ((const float4*)rp)[v];
            r[v * 4 + 0] = t4.x; r[v * 4 + 1] = t4.y;
            r[v * 4 + 2] = t4.z; r[v * 4 + 3] = t4.w;
        }
#pragma unroll
        for (int kx = 0; kx < 9; kx++) {
            float wv = wr[ky * 9 + kx];
#pragma unroll
            for (int ox = 0; ox < 20; ox++) acc[ox] += r[ox + kx] * wv;
        }
    }
    float* op = &h1[(b * 256 + c0 + co) * 400 + oy * 20];
#pragma unroll
    for (int v = 0; v < 5; v++) {
        float4 s4;
        s4.x = fmaxf(acc[v * 4 + 0], 0.f);
        s4.y = fmaxf(acc[v * 4 + 1], 0.f);
        s4.z = fmaxf(acc[v * 4 + 2], 0.f);
        s4.w = fmaxf(acc[v * 4 + 3], 0.f);
        ((float4*)op)[v] = s4;
    }
}

// ---------------- conv2: [C,256,20,20] -> u[C,1152,8] (transposed caps layout) ------
// grid C blocks (one per b), 256 threads (one per c_out). LDS stages 8 in-channels.
// u[b, i, p] with i = ox*192 + oy*32 + co/8, p = co%8  => addr b*9216 + ox*1536 + oy*256 + co
__global__ __launch_bounds__(256, 2) void conv2_k(const float* __restrict__ h1,
                                                  const float* __restrict__ w,
                                                  const float* __restrict__ bias,
                                                  float* __restrict__ u) {
    int b = blockIdx.x;
    int co = threadIdx.x;
    __shared__ float tile[8 * 400];
    float acc[36];
    float bv = bias[co];
#pragma unroll
    for (int k = 0; k < 36; k++) acc[k] = bv;

    const float* wp = &w[co * 20736];  // 256*81

    for (int ct = 0; ct < 32; ct++) {
        __syncthreads();
        const float4* src = (const float4*)&h1[(b * 256 + ct * 8) * 400];
        for (int t = threadIdx.x; t < 800; t += 256) ((float4*)tile)[t] = src[t];
        __syncthreads();

#pragma unroll 1
        for (int cc = 0; cc < 8; cc++) {
            const float* wq = &wp[(ct * 8 + cc) * 81];
            float wr[81];
#pragma unroll
            for (int k = 0; k < 81; k++) wr[k] = wq[k];
            const float* ip = &tile[cc * 400];
#pragma unroll
            for (int y = 0; y < 19; y++) {
                float r[20];
#pragma unroll
                for (int v = 0; v < 5; v++) {
                    float4 t4 = ((const float4*)&ip[y * 20])[v];
                    r[v * 4 + 0] = t4.x; r[v * 4 + 1] = t4.y;
                    r[v * 4 + 2] = t4.z; r[v * 4 + 3] = t4.w;
                }
#pragma unroll
                for (int oy = 0; oy < 6; oy++) {
                    int ky = y - 2 * oy;
                    if (ky >= 0 && ky < 9) {   // compile-time folded (y, oy unrolled)
#pragma unroll
                        for (int kx = 0; kx < 9; kx++) {
                            float wv = wr[ky * 9 + kx];
#pragma unroll
                            for (int ox = 0; ox < 6; ox++)
                                acc[oy * 6 + ox] += r[2 * ox + kx] * wv;
                        }
                    }
                }
            }
        }
    }
#pragma unroll
    for (int oy = 0; oy < 6; oy++)
#pragma unroll
        for (int ox = 0; ox < 6; ox++)
            u[b * 9216 + ox * 1536 + oy * 256 + co] = acc[oy * 6 + ox];
}

// ---------------- u_hat: u[b,i,p] x W[i,j,p,q] -> uhat[b][j*16+q][i] ----------------
// grid (18 i-tiles, C/8 b-tiles), 256 threads. i-tile=64, b-tile=8.
__global__ __launch_bounds__(256) void uhat_k(const float* __restrict__ u,
                                              const float* __restrict__ W,
                                              float* __restrict__ uhat) {
    int i0 = blockIdx.x * 64;
    int b0 = blockIdx.y * 8;
    __shared__ float ul[8 * 64 * 9];   // [bb][il][p], stride 9 (pad: conflict-free)
    __shared__ float wl[64 * 129];     // [il][p*16+q], stride 129 (pad)
    int tid = threadIdx.x;

    for (int t = tid; t < 4096; t += 256) {
        int bb = t >> 9, r = t & 511;
        ul[bb * 576 + (r >> 3) * 9 + (r & 7)] = u[(b0 + bb) * 9216 + i0 * 8 + r];
    }

    int il = tid & 63, g = tid >> 6;
    for (int j = 0; j < 10; j++) {
        __syncthreads();
        for (int t = tid; t < 2048; t += 256) {
            int li = t >> 5, off = (t & 31) * 4;
            float4 v = *(const float4*)&W[(i0 + li) * 1280 + j * 128 + off];
            float* d = &wl[li * 129 + off];
            d[0] = v.x; d[1] = v.y; d[2] = v.z; d[3] = v.w;
        }
        __syncthreads();
#pragma unroll 1
        for (int bb = 0; bb < 8; bb++) {
            float ur[8];
#pragma unroll
            for (int p = 0; p < 8; p++) ur[p] = ul[bb * 576 + il * 9 + p];
#pragma unroll
            for (int k = 0; k < 4; k++) {
                int q = g * 4 + k;
                float a = 0.f;
#pragma unroll
                for (int p = 0; p < 8; p++) a += ur[p] * wl[il * 129 + p * 16 + q];
                uhat[((b0 + bb) * 160 + j * 16 + q) * 1152 + i0 + il] = a;
            }
        }
    }
}

// ---------------- dynamic routing (3 iters) -> out[C,10,16] ----------------
// grid C (one per b), 256 threads. b_ij in registers (chunk-unrolled), c in LDS.
__global__ __launch_bounds__(256) void route_k(const float* __restrict__ uhat,
                                               float* __restrict__ out) {
    int b = blockIdx.x;
    int tid = threadIdx.x;
    __shared__ float c_lds[1152 * 10];
    __shared__ float s_lds[160];
    __shared__ float v_lds[160];
    const float* base = uhat + (size_t)b * 160 * 1152;

    float breg[5][10];
#pragma unroll
    for (int ch = 0; ch < 5; ch++)
#pragma unroll
        for (int j = 0; j < 10; j++) breg[ch][j] = 0.f;

    for (int t = 0; t < 3; t++) {
        // ---- phase A: coupling coefficients c ----
        if (t == 0) {
            for (int k = tid; k < 11520; k += 256) c_lds[k] = 0.1f;
        } else {
#pragma unroll
            for (int ch = 0; ch < 5; ch++) {
                int i = ch * 256 + tid;
                if (i < 1152) {
#pragma unroll
                    for (int j = 0; j < 10; j++) {
                        float d = 0.f;
#pragma unroll
                        for (int q = 0; q < 16; q++)
                            d += base[(j * 16 + q) * 1152 + i] * v_lds[j * 16 + q];
                        breg[ch][j] += d;
                    }
                    float m = breg[ch][0];
#pragma unroll
                    for (int j = 1; j < 10; j++) m = fmaxf(m, breg[ch][j]);
                    float e[10];
                    float sum = 0.f;
#pragma unroll
                    for (int j = 0; j < 10; j++) { e[j] = __expf(breg[ch][j] - m); sum += e[j]; }
                    float inv = 1.0f / sum;
#pragma unroll
                    for (int j = 0; j < 10; j++) c_lds[i * 10 + j] = e[j] * inv;
                }
            }
        }
        __syncthreads();
        // ---- phase B: s_jq = sum_i c_ij * uhat_ijq ----
        if (tid < 160) {
            int j = tid >> 4;
            const float* up = base + tid * 1152;
            const float* cp = c_lds + j;
            float s0 = 0.f, s1 = 0.f, s2 = 0.f, s3 = 0.f;
            for (int i = 0; i < 1152; i += 4) {
                float4 uv = *(const float4*)&up[i];
                s0 += uv.x * cp[(i + 0) * 10];
                s1 += uv.y * cp[(i + 1) * 10];
                s2 += uv.z * cp[(i + 2) * 10];
                s3 += uv.w * cp[(i + 3) * 10];
            }
            s_lds[tid] = (s0 + s1) + (s2 + s3);
        }
        __syncthreads();
        // ---- squash ----
        if (tid < 10) {
            float sq = 0.f;
#pragma unroll
            for (int q = 0; q < 16; q++) { float x = s_lds[tid * 16 + q]; sq += x * x; }
            float norm = sqrtf(sq + 1e-8f);
            float scale = (sq / (1.0f + sq)) / norm;
#pragma unroll
            for (int q = 0; q < 16; q++) v_lds[tid * 16 + q] = s_lds[tid * 16 + q] * scale;
        }
        __syncthreads();
    }
    if (tid < 160) out[b * 160 + tid] = v_lds[tid];
}

extern "C" void kernel_launch(void* const* d_in, const int* in_sizes, int n_in,
                              void* d_out, int out_size, void* d_ws, size_t ws_size,
                              hipStream_t stream) {
    const float* input = (const float*)d_in[0];
    const float* c1w = (const float*)d_in[1];
    const float* c1b = (const float*)d_in[2];
    const float* c2w = (const float*)d_in[3];
    const float* c2b = (const float*)d_in[4];
    const float* capW = (const float*)d_in[5];
    float* out = (float*)d_out;
    float* ws = (float*)d_ws;

    // Pick the largest batch-chunk C (divisor of 512, >=8) whose footprint fits ws_size.
    // Footprint per chunk: u = C*9216 floats, then max(h1 = C*102400, uhat = C*184320)
    // (h1 aliases uhat; h1 fully consumed by conv2 before uhat_k writes).
    int C = 0;
    const int cands[7] = {512, 256, 128, 64, 32, 16, 8};
    for (int k = 0; k < 7; k++) {
        size_t need = (size_t)cands[k] * 193536 * sizeof(float);
        if (need <= ws_size) { C = cands[k]; break; }
    }
    if (C == 0) return;  // < 6.2 MB workspace: cannot run

    float* u_buf = ws;                       // C*9216 floats
    float* uhat  = ws + (size_t)C * 9216;    // C*184320 floats
    float* h1    = uhat;                     // aliases uhat region

    for (int b0 = 0; b0 < 512; b0 += C) {
        conv1_k<<<C * 16, 320, 0, stream>>>(input + (size_t)b0 * 784, c1w, c1b, h1);
        conv2_k<<<C, 256, 0, stream>>>(h1, c2w, c2b, u_buf);
        uhat_k<<<dim3(18, C / 8), 256, 0, stream>>>(u_buf, capW, uhat);
        route_k<<<C, 256, 0, stream>>>(uhat, out + (size_t)b0 * 160);
    }
}